// Round 11
// baseline (582.344 us; speedup 1.0000x reference)
//
#include <hip/hip_runtime.h>

#define NNODES 50000
#define NEDGES 800000
#define INDIM  512
#define OUTD   512   // NUM_HEADS * OUT_DIM
#define NHEADS 8

typedef float  f32x4  __attribute__((ext_vector_type(4)));
typedef __bf16 bf16x8 __attribute__((ext_vector_type(8)));

__device__ __forceinline__ float lrelu(float x) { return x > 0.f ? x : 0.2f * x; }

// ---------------------------------------------------------------------------
// cvt: f32 -> bf16 for feat and W in one launch, vectorized 8/thread (G13)
// ---------------------------------------------------------------------------
__global__ __launch_bounds__(256) void cvt2_k(
    const float* __restrict__ fa, __bf16* __restrict__ oa, int na8,
    const float* __restrict__ fb, __bf16* __restrict__ ob, int nb8)
{
    int i0 = blockIdx.x * 256 + threadIdx.x;
    int stride = gridDim.x * 256;
    for (int i = i0; i < na8; i += stride) {
        f32x4 a = *(const f32x4*)(fa + (size_t)i * 8);
        f32x4 b = *(const f32x4*)(fa + (size_t)i * 8 + 4);
        bf16x8 v;
        v[0]=(__bf16)a[0]; v[1]=(__bf16)a[1]; v[2]=(__bf16)a[2]; v[3]=(__bf16)a[3];
        v[4]=(__bf16)b[0]; v[5]=(__bf16)b[1]; v[6]=(__bf16)b[2]; v[7]=(__bf16)b[3];
        *(bf16x8*)(oa + (size_t)i * 8) = v;
    }
    for (int i = i0; i < nb8; i += stride) {
        f32x4 a = *(const f32x4*)(fb + (size_t)i * 8);
        f32x4 b = *(const f32x4*)(fb + (size_t)i * 8 + 4);
        bf16x8 v;
        v[0]=(__bf16)a[0]; v[1]=(__bf16)a[1]; v[2]=(__bf16)a[2]; v[3]=(__bf16)a[3];
        v[4]=(__bf16)b[0]; v[5]=(__bf16)b[1]; v[6]=(__bf16)b[2]; v[7]=(__bf16)b[3];
        *(bf16x8*)(ob + (size_t)i * 8) = v;
    }
}

// ---------------------------------------------------------------------------
// GEMM v3: h = leaky_relu(featb @ Wb^T + b), bf16 MFMA, f32 acc.
// Tile 128x256, BK=64, 512 threads = 8 waves (2 row x 4 col); per wave 64x64.
// Single-buffer m97 structure (stage -> sync -> compute -> sync): 48 KB LDS
// -> 3 blocks/CU, 24 waves/CU. global_load_lds width=16; XOR swizzle via
// pre-swizzled global source + swizzled ds_read. Grid (2 cols, 391 rows):
// featb logical re-read 2x (was 4x). Fused edge histogram + logits epilogue.
// ---------------------------------------------------------------------------
constexpr int BM = 128, BN = 256;

__global__ __launch_bounds__(512) void gemm_h(
    const __bf16* __restrict__ featb, const __bf16* __restrict__ Wb,
    const float* __restrict__ bias, const float* __restrict__ w_s,
    const float* __restrict__ w_d, __bf16* __restrict__ hout,
    float* __restrict__ esrc, float* __restrict__ edst,
    const int* __restrict__ dstv, int* __restrict__ deg)
{
    __shared__ __bf16 As[BM][64];   // 16 KB
    __shared__ __bf16 Bs[BN][64];   // 32 KB
    const int col0 = blockIdx.x * BN;     // 2 col tiles
    const int row0 = blockIdx.y * BM;     // 391 row tiles
    const int tid  = threadIdx.x;

    // ---- fused edge histogram: this block's 1024-edge slice ----
    {
        int bid = blockIdx.y * gridDim.x + blockIdx.x;   // 0..781
        int lo = bid * 1024, hi = lo + 1024;
        if (hi > NEDGES) hi = NEDGES;
        for (int e = lo + tid; e < hi; e += 512)
            atomicAdd(&deg[dstv[e]], 1);
    }

    const int lane = tid & 63;
    const int w    = tid >> 6;          // 0..7
    const int wr   = w >> 2, wc = w & 3;
    const int lr   = lane & 15, kg = lane >> 4;

    // staging source offsets (pre-swizzled: sub = ps ^ (r&7), involution
    // with the read-side XOR; LDS dest stays linear — rule #21)
    int srcA[2], srcB[4];
    #pragma unroll
    for (int i = 0; i < 2; ++i) {                 // A: 1024 chunks
        int p = tid + 512 * i;
        int r = p >> 3, ps = p & 7, sub = ps ^ (r & 7);
        int gra = row0 + r; if (gra > NNODES - 1) gra = NNODES - 1;
        srcA[i] = gra * INDIM + sub * 8;
    }
    #pragma unroll
    for (int i = 0; i < 4; ++i) {                 // B: 2048 chunks
        int p = tid + 512 * i;
        int r = p >> 3, ps = p & 7, sub = ps ^ (r & 7);
        srcB[i] = (col0 + r) * INDIM + sub * 8;
    }

    f32x4 acc[4][4] = {};

    for (int k0 = 0; k0 < INDIM; k0 += 64) {
        #pragma unroll
        for (int i = 0; i < 2; ++i) {
            int p = tid + 512 * i;
            __builtin_amdgcn_global_load_lds(
                (const __attribute__((address_space(1))) void*)(featb + srcA[i] + k0),
                (__attribute__((address_space(3))) void*)((char*)&As[0][0] + p * 16),
                16, 0, 0);
        }
        #pragma unroll
        for (int i = 0; i < 4; ++i) {
            int p = tid + 512 * i;
            __builtin_amdgcn_global_load_lds(
                (const __attribute__((address_space(1))) void*)(Wb + srcB[i] + k0),
                (__attribute__((address_space(3))) void*)((char*)&Bs[0][0] + p * 16),
                16, 0, 0);
        }
        __syncthreads();   // drains vmcnt: tile resident
        #pragma unroll
        for (int ks = 0; ks < 2; ++ks) {
            bf16x8 af[4], bf[4];
            const int c = ks * 4 + kg;
            #pragma unroll
            for (int mi = 0; mi < 4; ++mi) {
                int r = wr * 64 + mi * 16 + lr;
                af[mi] = *(const bf16x8*)((const char*)&As[0][0] + r * 128 + (c ^ (r & 7)) * 16);
            }
            #pragma unroll
            for (int ni = 0; ni < 4; ++ni) {
                int r = wc * 64 + ni * 16 + lr;
                bf[ni] = *(const bf16x8*)((const char*)&Bs[0][0] + r * 128 + (c ^ (r & 7)) * 16);
            }
            #pragma unroll
            for (int mi = 0; mi < 4; ++mi)
                #pragma unroll
                for (int ni = 0; ni < 4; ++ni)
                    acc[mi][ni] = __builtin_amdgcn_mfma_f32_16x16x32_bf16(af[mi], bf[ni], acc[mi][ni], 0, 0, 0);
        }
        __syncthreads();
    }

    // epilogue: bias + leakyrelu, store bf16 h, fused per-head logits
    float cb[4], wsv[4], wdv[4];
    #pragma unroll
    for (int ni = 0; ni < 4; ++ni) {
        int c = col0 + wc * 64 + ni * 16 + lr;
        cb[ni]  = bias[c];
        wsv[ni] = w_s[c];
        wdv[ni] = w_d[c];
    }
    const int head = (col0 + wc * 64) >> 6;   // wave spans exactly one head
    #pragma unroll
    for (int mi = 0; mi < 4; ++mi) {
        #pragma unroll
        for (int reg = 0; reg < 4; ++reg) {
            int r = row0 + wr * 64 + mi * 16 + kg * 4 + reg;   // C/D: row=(l>>4)*4+reg
            bool valid = r < NNODES;
            float vs = 0.f, vd = 0.f;
            #pragma unroll
            for (int ni = 0; ni < 4; ++ni) {
                int c = col0 + wc * 64 + ni * 16 + lr;          // C/D: col=l&15
                float v = acc[mi][ni][reg] + cb[ni];
                v = lrelu(v);
                if (valid) hout[(size_t)r * OUTD + c] = (__bf16)v;
                vs += v * wsv[ni];
                vd += v * wdv[ni];
            }
            #pragma unroll
            for (int m = 1; m < 16; m <<= 1) { vs += __shfl_xor(vs, m); vd += __shfl_xor(vd, m); }
            if (valid && lr == 0) {
                esrc[r * NHEADS + head] = vs;
                edst[r * NHEADS + head] = vd;
            }
        }
    }
}

// ---------------------------------------------------------------------------
// CSR scan: single block, 1024 threads x 49 nodes each (50176 >= 50000).
// Per-thread serial sum -> block Hillis-Steele scan -> write offs + cursor.
// ---------------------------------------------------------------------------
__global__ __launch_bounds__(1024) void scan_all(
    const int* __restrict__ deg, int* __restrict__ offs, int* __restrict__ cursor)
{
    __shared__ int sd[1024];
    const int t = threadIdx.x;
    const int CH = 49;
    const int base = t * CH;
    int s = 0;
    for (int i = 0; i < CH; ++i) {
        int idx = base + i;
        if (idx < NNODES) s += deg[idx];
    }
    sd[t] = s;
    __syncthreads();
    int val = s;
    for (int st = 1; st < 1024; st <<= 1) {
        int add = (t >= st) ? sd[t - st] : 0;
        __syncthreads();
        val += add; sd[t] = val;
        __syncthreads();
    }
    int run = val - s;   // exclusive prefix of this thread's chunk
    for (int i = 0; i < CH; ++i) {
        int idx = base + i;
        if (idx < NNODES) {
            offs[idx] = run; cursor[idx] = run;
            run += deg[idx];
        }
    }
    if (t == 0) offs[NNODES] = NEDGES;
}

// scatter writes {src, e} packed — agg needs no eidx->src indirection
__global__ void scatter_k(const int* __restrict__ dstv, const int* __restrict__ src,
                          int* __restrict__ cursor, int2* __restrict__ perm)
{
    int e = blockIdx.x * blockDim.x + threadIdx.x;
    if (e < NEDGES) {
        int pos = atomicAdd(&cursor[dstv[e]], 1);
        perm[pos] = make_int2(src[e], e);
    }
}

// ---------------------------------------------------------------------------
// Aggregation (fused softmax): one wave per dst node; lane l owns cols
// [8l, 8l+8), head = l>>3. Max-free softmax (logits bounded ~±45 << 88).
// Unroll x4 (VGPR 36, high occupancy — measured equal to x8 at plateau:
// agg_k delivers ~6.4 TB/s combined, at the streaming ceiling).
// ---------------------------------------------------------------------------
__global__ __launch_bounds__(256) void agg_k(
    const int* __restrict__ offs, const int2* __restrict__ perm,
    const float* __restrict__ esrc, const float* __restrict__ edst,
    const float* __restrict__ dist, const __bf16* __restrict__ hmat,
    float* __restrict__ out)
{
    int node = blockIdx.x * 4 + (threadIdx.x >> 6);
    int lane = threadIdx.x & 63;
    if (node >= NNODES) return;
    const int head = lane >> 3;
    const float edv = edst[(size_t)node * NHEADS + head];
    int beg = offs[node], end = offs[node + 1];
    float denom = 0.f;
    float acc[8] = {};

    int pos = beg;
    for (; pos + 4 <= end; pos += 4) {
        int2 a0 = perm[pos], a1 = perm[pos + 1], a2 = perm[pos + 2], a3 = perm[pos + 3];
        float es0 = esrc[(size_t)a0.x * NHEADS + head];
        float es1 = esrc[(size_t)a1.x * NHEADS + head];
        float es2 = esrc[(size_t)a2.x * NHEADS + head];
        float es3 = esrc[(size_t)a3.x * NHEADS + head];
        float di0 = dist[(size_t)a0.y * NHEADS + head];
        float di1 = dist[(size_t)a1.y * NHEADS + head];
        float di2 = dist[(size_t)a2.y * NHEADS + head];
        float di3 = dist[(size_t)a3.y * NHEADS + head];
        bf16x8 h0 = *(const bf16x8*)(hmat + (size_t)a0.x * OUTD + lane * 8);
        bf16x8 h1 = *(const bf16x8*)(hmat + (size_t)a1.x * OUTD + lane * 8);
        bf16x8 h2 = *(const bf16x8*)(hmat + (size_t)a2.x * OUTD + lane * 8);
        bf16x8 h3 = *(const bf16x8*)(hmat + (size_t)a3.x * OUTD + lane * 8);
        float ex0 = __expf(lrelu(es0 + edv));
        float ex1 = __expf(lrelu(es1 + edv));
        float ex2 = __expf(lrelu(es2 + edv));
        float ex3 = __expf(lrelu(es3 + edv));
        denom += (ex0 + ex1) + (ex2 + ex3);
        float w0 = ex0 * di0, w1 = ex1 * di1, w2 = ex2 * di2, w3 = ex3 * di3;
        #pragma unroll
        for (int j = 0; j < 8; ++j)
            acc[j] += (w0 * (float)h0[j] + w1 * (float)h1[j])
                    + (w2 * (float)h2[j] + w3 * (float)h3[j]);
    }
    for (; pos < end; ++pos) {
        int2 a0 = perm[pos];
        float es0 = esrc[(size_t)a0.x * NHEADS + head];
        float di0 = dist[(size_t)a0.y * NHEADS + head];
        bf16x8 h0 = *(const bf16x8*)(hmat + (size_t)a0.x * OUTD + lane * 8);
        float ex0 = __expf(lrelu(es0 + edv));
        denom += ex0;
        float w0 = ex0 * di0;
        #pragma unroll
        for (int j = 0; j < 8; ++j) acc[j] += w0 * (float)h0[j];
    }

    float sinv = denom > 0.f ? 1.f / denom : 0.f;
    f32x4 o0 = {acc[0] * sinv, acc[1] * sinv, acc[2] * sinv, acc[3] * sinv};
    f32x4 o1 = {acc[4] * sinv, acc[5] * sinv, acc[6] * sinv, acc[7] * sinv};
    *(f32x4*)(out + (size_t)node * OUTD + lane * 8)     = o0;
    *(f32x4*)(out + (size_t)node * OUTD + lane * 8 + 4) = o1;
}

// ---------------------------------------------------------------------------
extern "C" void kernel_launch(void* const* d_in, const int* in_sizes, int n_in,
                              void* d_out, int out_size, void* d_ws, size_t ws_size,
                              hipStream_t stream)
{
    const float* feat = (const float*)d_in[0];
    const float* dist = (const float*)d_in[1];
    const int*   src  = (const int*)d_in[2];
    const int*   dstv = (const int*)d_in[3];
    const float* W    = (const float*)d_in[4];
    const float* bias = (const float*)d_in[5];
    const float* w_s  = (const float*)d_in[6];
    const float* w_d  = (const float*)d_in[7];
    float* out = (float*)d_out;

    char* wsb = (char*)d_ws;
    size_t off = 0;
    auto alloc = [&](size_t bytes) -> char* {
        char* r = wsb + off;
        off = (off + bytes + 255) & ~(size_t)255;
        return r;
    };
    __bf16* hmat  = (__bf16*)alloc((size_t)NNODES * OUTD * 2);   // 51.2 MB
    __bf16* featb = (__bf16*)alloc((size_t)NNODES * INDIM * 2);  // 51.2 MB
    __bf16* Wb    = (__bf16*)alloc((size_t)OUTD * INDIM * 2);    // 0.5 MB
    float*  esrc  = (float*)alloc((size_t)NNODES * NHEADS * 4);  // 1.6 MB
    float*  edst  = (float*)alloc((size_t)NNODES * NHEADS * 4);
    int*    deg   = (int*)alloc((size_t)NNODES * 4);
    int*    offs  = (int*)alloc((size_t)(NNODES + 1) * 4);
    int*    cursor= (int*)alloc((size_t)NNODES * 4);
    int2*   perm  = (int2*)alloc((size_t)NEDGES * 8);            // 6.4 MB
    int*    bsums = (int*)alloc(64 * 4);

    hipMemsetAsync(deg, 0, (size_t)NNODES * 4, stream);

    cvt2_k<<<2048, 256, 0, stream>>>(feat, featb, NNODES * INDIM / 8,
                                     W, Wb, OUTD * INDIM / 8);

    gemm_h<<<dim3(OUTD / BN, (NNODES + BM - 1) / BM), 512, 0, stream>>>(
        featb, Wb, bias, w_s, w_d, hmat, esrc, edst, dstv, deg);

    scan_all<<<1, 1024, 0, stream>>>(deg, offs, cursor);
    scatter_k<<<(NEDGES + 255) / 256, 256, 0, stream>>>(dstv, src, cursor, perm);

    agg_k<<<(NNODES + 3) / 4, 256, 0, stream>>>(offs, perm, esrc, edst, dist, hmat, out);
}